// Round 1
// baseline (251.236 us; speedup 1.0000x reference)
//
#include <hip/hip_runtime.h>
#include <hip/hip_bf16.h>
#include <stdint.h>

// Problem constants
#define BT     32768      // B*T rows
#define CIN    512
#define NE     640        // GROUP*ENTRY
#define ENTRY  320
#define DD     256        // COUT/GROUP
#define MROWS  64         // rows per block
#define TPB    512        // 8 waves

using bf16x8 = __attribute__((ext_vector_type(8))) short;
using f32x4  = __attribute__((ext_vector_type(4))) float;

// LDS layout (bytes)
#define Y_OFF   0                  // 64 rows x stride 648 bf16 = 82944
#define Y_STR   648                // elems; 1296B row stride (16B aligned, word%32==4 -> 2-way banks)
#define S_OFF   82944              // 64 fp32 row sums
#define A_OFF   83200              // x tile: 64 rows x 80B (40 bf16, 32 used + pad)
#define A_STR   80
#define B_OFF   88320              // Wp tile: 2560 chunks x 16B = 40960
#define CB_OFF  83200              // cb tiles (phase 3, unions with A/B): 2048 chunks x 16B = 32768
#define SMEM_BYTES 129280

__device__ __forceinline__ unsigned short f2b(float f) {
    union { float f; uint32_t u; } v; v.f = f;
    uint32_t u = v.u;
    return (unsigned short)((u + 0x7FFFu + ((u >> 16) & 1u)) >> 16);
}

__device__ __forceinline__ void gl2lds16(const void* g, void* l) {
    __builtin_amdgcn_global_load_lds((const __attribute__((address_space(1))) void*)g,
                                     (__attribute__((address_space(3))) void*)l, 16, 0, 0);
}

// Prep: Wp (fp32 [640,512]) -> WpB (bf16), codebooks (fp32 [2,320,256]) -> cbT (bf16 [2,256,320])
__global__ void prep_kernel(const float* __restrict__ Wp, const float* __restrict__ cb,
                            unsigned short* __restrict__ WpB, unsigned short* __restrict__ cbT) {
    int i = blockIdx.x * blockDim.x + threadIdx.x;
    if (i < NE * CIN) {
        WpB[i] = f2b(Wp[i]);
    } else {
        int o = i - NE * CIN;
        if (o < 2 * ENTRY * DD) {
            int g = o / (DD * ENTRY);
            int r = o - g * (DD * ENTRY);
            int d = r / ENTRY;
            int e = r - d * ENTRY;
            cbT[o] = f2b(cb[(g * ENTRY + e) * DD + d]);
        }
    }
}

__global__ __launch_bounds__(TPB, 2) void fused_kernel(
    const float* __restrict__ x, const float* __restrict__ bp,
    const float* __restrict__ gum, const unsigned short* __restrict__ WpB,
    const unsigned short* __restrict__ cbT, float* __restrict__ out) {

    extern __shared__ char smem[];
    unsigned short* yS = (unsigned short*)(smem + Y_OFF);
    float*          sS = (float*)(smem + S_OFF);
    char*           aS = smem + A_OFF;
    char*           bS = smem + B_OFF;
    char*           cS = smem + CB_OFF;

    const int tid = threadIdx.x;
    const int w  = tid >> 6;     // wave 0..7
    const int l  = tid & 63;     // lane
    const int q  = l >> 4;       // quad 0..3
    const int ln = l & 15;
    const int rowbase = blockIdx.x * MROWS;

    if (tid < MROWS) sS[tid] = 0.0f;

    // ---------------- Phase 1: logits = x @ Wp^T ----------------
    f32x4 acc1[4][5];
    const f32x4 fz = {0.f, 0.f, 0.f, 0.f};
#pragma unroll
    for (int rt = 0; rt < 4; ++rt)
#pragma unroll
        for (int ct = 0; ct < 5; ++ct) acc1[rt][ct] = fz;

    // A-stage mapping: each thread loads float4 of x
    const int ar  = tid >> 3;   // row 0..63
    const int akq = tid & 7;    // 4-float quarter
    const float* xrow = x + (rowbase + ar) * CIN + akq * 4;

#pragma unroll 1
    for (int ks = 0; ks < 16; ++ks) {
        const int k0 = ks * 32;
        __syncthreads();
        // stage A (fp32 -> bf16)
        float4 xv = *(const float4*)(xrow + k0);
        ushort4 hv;
        hv.x = f2b(xv.x); hv.y = f2b(xv.y); hv.z = f2b(xv.z); hv.w = f2b(xv.w);
        *(ushort4*)(aS + ar * A_STR + akq * 8) = hv;
        // stage B (Wp bf16) via global_load_lds, chunk-XOR swizzle
#pragma unroll
        for (int i = 0; i < 5; ++i) {
            int cbase = i * 512 + (w << 6);
            int c = cbase + l;
            int e = c >> 2;
            int q2 = (c & 3) ^ ((e >> 1) & 3);
            gl2lds16(WpB + e * CIN + k0 + q2 * 8, bS + cbase * 16);
        }
        __syncthreads();
        bf16x8 af[4];
#pragma unroll
        for (int rt = 0; rt < 4; ++rt)
            af[rt] = *(const bf16x8*)(aS + (rt * 16 + ln) * A_STR + q * 16);
        bf16x8 bfr[5];
#pragma unroll
        for (int ct = 0; ct < 5; ++ct) {
            int e = w * 80 + ct * 16 + ln;
            int ch = e * 4 + (q ^ ((e >> 1) & 3));
            bfr[ct] = *(const bf16x8*)(bS + ch * 16);
        }
#pragma unroll
        for (int rt = 0; rt < 4; ++rt)
#pragma unroll
            for (int ct = 0; ct < 5; ++ct)
                acc1[rt][ct] = __builtin_amdgcn_mfma_f32_16x16x32_bf16(af[rt], bfr[ct], acc1[rt][ct], 0, 0, 0);
    }

    // ---------------- Phase 2: exp + row sums ----------------
    float bpv[5];
#pragma unroll
    for (int ct = 0; ct < 5; ++ct) bpv[ct] = bp[w * 80 + ct * 16 + ln];

#pragma unroll
    for (int rt = 0; rt < 4; ++rt) {
#pragma unroll
        for (int r = 0; r < 4; ++r) {
            int row = rt * 16 + q * 4 + r;
            int grow = (rowbase + row) * NE;
            float p = 0.f;
#pragma unroll
            for (int ct = 0; ct < 5; ++ct) {
                int col = w * 80 + ct * 16 + ln;
                float v = acc1[rt][ct][r] + bpv[ct] + gum[grow + col];
                float e = __expf(v);
                yS[row * Y_STR + col] = f2b(e);
                p += e;
            }
            p += __shfl_xor(p, 1);
            p += __shfl_xor(p, 2);
            p += __shfl_xor(p, 4);
            p += __shfl_xor(p, 8);
            if (ln == 0) atomicAdd(&sS[row], p);
        }
    }

    // ---------------- Phase 3: out = (y @ cb) / S ----------------
    f32x4 acc2[4][4];
#pragma unroll
    for (int rt = 0; rt < 4; ++rt)
#pragma unroll
        for (int ct = 0; ct < 4; ++ct) acc2[rt][ct] = fz;

    const int g  = w >> 2;          // group
    const int nb = (w & 3) * 64;    // col block within group

#pragma unroll 1
    for (int ks = 0; ks < 10; ++ks) {
        const int k0 = ks * 32;
        __syncthreads();   // also orders phase-2 y/S writes before reads
#pragma unroll
        for (int i = 0; i < 4; ++i) {
            int cbase = i * 512 + (w << 6);
            int c = cbase + l;
            int gg = c >> 10;
            int cc = c & 1023;
            int n = cc >> 2;
            int q2 = (cc & 3) ^ ((n >> 1) & 3);
            gl2lds16(cbT + (gg * DD + n) * ENTRY + k0 + q2 * 8, cS + cbase * 16);
        }
        __syncthreads();
        bf16x8 af[4];
#pragma unroll
        for (int rt = 0; rt < 4; ++rt)
            af[rt] = *(const bf16x8*)((char*)yS + (rt * 16 + ln) * (Y_STR * 2) + (g * ENTRY + k0 + q * 8) * 2);
        bf16x8 bfr[4];
#pragma unroll
        for (int ct = 0; ct < 4; ++ct) {
            int n = nb + ct * 16 + ln;
            int ch = (g << 10) + n * 4 + (q ^ ((n >> 1) & 3));
            bfr[ct] = *(const bf16x8*)(cS + ch * 16);
        }
#pragma unroll
        for (int rt = 0; rt < 4; ++rt)
#pragma unroll
            for (int ct = 0; ct < 4; ++ct)
                acc2[rt][ct] = __builtin_amdgcn_mfma_f32_16x16x32_bf16(af[rt], bfr[ct], acc2[rt][ct], 0, 0, 0);
    }

    // epilogue: divide by softmax denom, store fp32
#pragma unroll
    for (int rt = 0; rt < 4; ++rt) {
#pragma unroll
        for (int r = 0; r < 4; ++r) {
            int row = rt * 16 + q * 4 + r;
            float inv = 1.0f / sS[row];
            int orow = (rowbase + row) * 512;
#pragma unroll
            for (int ct = 0; ct < 4; ++ct) {
                int col = g * DD + nb + ct * 16 + ln;
                out[orow + col] = acc2[rt][ct][r] * inv;
            }
        }
    }
}

extern "C" void kernel_launch(void* const* d_in, const int* in_sizes, int n_in,
                              void* d_out, int out_size, void* d_ws, size_t ws_size,
                              hipStream_t stream) {
    const float* x   = (const float*)d_in[0];
    const float* Wp  = (const float*)d_in[1];
    const float* bp  = (const float*)d_in[2];
    const float* cb  = (const float*)d_in[3];
    const float* gum = (const float*)d_in[4];
    float* out = (float*)d_out;

    unsigned short* WpB = (unsigned short*)d_ws;
    unsigned short* cbT = WpB + NE * CIN;

    int prep_total = NE * CIN + 2 * ENTRY * DD;
    prep_kernel<<<(prep_total + 255) / 256, 256, 0, stream>>>(Wp, cb, WpB, cbT);

    fused_kernel<<<dim3(BT / MROWS), dim3(TPB), SMEM_BYTES, stream>>>(x, bp, gum, WpB, cbT, out);
}

// Round 2
// 251.016 us; speedup vs baseline: 1.0009x; 1.0009x over previous
//
#include <hip/hip_runtime.h>
#include <hip/hip_bf16.h>
#include <stdint.h>

// Problem constants
#define BT     32768      // B*T rows
#define CIN    512
#define NE     640        // GROUP*ENTRY
#define ENTRY  320
#define DD     256        // COUT/GROUP
#define MROWS  32         // rows per block
#define TPB    256        // 4 waves

using bf16x8 = __attribute__((ext_vector_type(8))) short;
using f32x4  = __attribute__((ext_vector_type(4))) float;

// LDS layout (bytes) — phase-1 staging UNIONs with y/cb (y written only in phase 2)
// phase 1: A [0,2560) + B [2560,43520)
// phase 2/3: y [0,41472) + S [41472,41600) + cb [41600,74368)
#define A_OFF   0
#define A_STR   80                 // bytes per row (32 bf16 used + pad); word%32=20 -> 2-way
#define B_OFF   2560
#define Y_OFF   0
#define Y_STR   648                // elems; 1296B row stride, word%32=4 -> 2-way
#define S_OFF   41472
#define CB_OFF  41600
#define SMEM_BYTES 74368           // 2 blocks/CU (148.7KB < 160KB)

__device__ __forceinline__ unsigned short f2b(float f) {
    union { float f; uint32_t u; } v; v.f = f;
    uint32_t u = v.u;
    return (unsigned short)((u + 0x7FFFu + ((u >> 16) & 1u)) >> 16);
}

__device__ __forceinline__ void gl2lds16(const void* g, void* l) {
    __builtin_amdgcn_global_load_lds((const __attribute__((address_space(1))) void*)g,
                                     (__attribute__((address_space(3))) void*)l, 16, 0, 0);
}

// Prep: Wp (fp32 [640,512]) -> WpB (bf16), codebooks (fp32 [2,320,256]) -> cbT (bf16 [2,256,320])
__global__ void prep_kernel(const float* __restrict__ Wp, const float* __restrict__ cb,
                            unsigned short* __restrict__ WpB, unsigned short* __restrict__ cbT) {
    int i = blockIdx.x * blockDim.x + threadIdx.x;
    if (i < NE * CIN) {
        WpB[i] = f2b(Wp[i]);
    } else {
        int o = i - NE * CIN;
        if (o < 2 * ENTRY * DD) {
            int g = o / (DD * ENTRY);
            int r = o - g * (DD * ENTRY);
            int d = r / ENTRY;
            int e = r - d * ENTRY;
            cbT[o] = f2b(cb[(g * ENTRY + e) * DD + d]);
        }
    }
}

__global__ __launch_bounds__(TPB, 2) void fused_kernel(
    const float* __restrict__ x, const float* __restrict__ bp,
    const float* __restrict__ gum, const unsigned short* __restrict__ WpB,
    const unsigned short* __restrict__ cbT, float* __restrict__ out) {

    extern __shared__ char smem[];
    unsigned short* yS = (unsigned short*)(smem + Y_OFF);
    float*          sS = (float*)(smem + S_OFF);
    char*           aS = smem + A_OFF;
    char*           bS = smem + B_OFF;
    char*           cS = smem + CB_OFF;

    const int tid = threadIdx.x;
    const int w  = tid >> 6;     // wave 0..3
    const int l  = tid & 63;     // lane
    const int q  = l >> 4;       // quad 0..3
    const int ln = l & 15;
    const int rowbase = blockIdx.x * MROWS;

    // ---------------- Phase 1: logits = x @ Wp^T ----------------
    f32x4 acc1[2][10];
    const f32x4 fz = {0.f, 0.f, 0.f, 0.f};
#pragma unroll
    for (int rt = 0; rt < 2; ++rt)
#pragma unroll
        for (int ct = 0; ct < 10; ++ct) acc1[rt][ct] = fz;

    // A-stage mapping: 256 threads x float4 = 32 rows x 8 quarters
    const int ar  = tid >> 3;   // row 0..31
    const int akq = tid & 7;    // 4-float quarter
    const float* xrow = x + (rowbase + ar) * CIN + akq * 4;

#pragma unroll 1
    for (int ks = 0; ks < 16; ++ks) {
        const int k0 = ks * 32;
        __syncthreads();
        // stage A (fp32 -> bf16)
        float4 xv = *(const float4*)(xrow + k0);
        ushort4 hv;
        hv.x = f2b(xv.x); hv.y = f2b(xv.y); hv.z = f2b(xv.z); hv.w = f2b(xv.w);
        *(ushort4*)(aS + ar * A_STR + akq * 8) = hv;
        // stage B (Wp bf16): 2560 chunks of 16B, chunk-XOR swizzle
#pragma unroll
        for (int i = 0; i < 10; ++i) {
            int cbase = i * 256 + (w << 6);
            int c = cbase + l;
            int e = c >> 2;
            int q2 = (c & 3) ^ ((e >> 1) & 3);
            gl2lds16(WpB + e * CIN + k0 + q2 * 8, bS + cbase * 16);
        }
        __syncthreads();
        bf16x8 af[2];
#pragma unroll
        for (int rt = 0; rt < 2; ++rt)
            af[rt] = *(const bf16x8*)(aS + (rt * 16 + ln) * A_STR + q * 16);
        bf16x8 bfr[10];
#pragma unroll
        for (int ct = 0; ct < 10; ++ct) {
            int e = w * 160 + ct * 16 + ln;
            int ch = e * 4 + (q ^ ((e >> 1) & 3));
            bfr[ct] = *(const bf16x8*)(bS + ch * 16);
        }
#pragma unroll
        for (int rt = 0; rt < 2; ++rt)
#pragma unroll
            for (int ct = 0; ct < 10; ++ct)
                acc1[rt][ct] = __builtin_amdgcn_mfma_f32_16x16x32_bf16(af[rt], bfr[ct], acc1[rt][ct], 0, 0, 0);
    }

    // ---------------- Phase 2: exp + row sums (y overwrites A/B staging) ----------------
    __syncthreads();                       // phase-1 LDS reads complete
    if (tid < MROWS) sS[tid] = 0.0f;
    __syncthreads();

    float bpv[10];
#pragma unroll
    for (int ct = 0; ct < 10; ++ct) bpv[ct] = bp[w * 160 + ct * 16 + ln];

    const float* gbase = gum + (size_t)rowbase * NE + w * 160 + ln;
    // software-pipelined gumbel loads: prefetch next row while processing current
    float gv[10];
    {
        const float* p0 = gbase + (size_t)(q * 4) * NE;   // ri=0 -> row q*4
#pragma unroll
        for (int ct = 0; ct < 10; ++ct) gv[ct] = p0[ct * 16];
    }
#pragma unroll
    for (int ri = 0; ri < 8; ++ri) {
        float gn[10];
        if (ri < 7) {
            int nrow = ((ri + 1) >> 2) * 16 + q * 4 + ((ri + 1) & 3);
            const float* pn = gbase + (size_t)nrow * NE;
#pragma unroll
            for (int ct = 0; ct < 10; ++ct) gn[ct] = pn[ct * 16];
        }
        int rt = ri >> 2, r = ri & 3;
        int row = rt * 16 + q * 4 + r;
        float p = 0.f;
#pragma unroll
        for (int ct = 0; ct < 10; ++ct) {
            int col = w * 160 + ct * 16 + ln;
            float v = acc1[rt][ct][r] + bpv[ct] + gv[ct];
            float e = __expf(v);
            yS[row * Y_STR + col] = f2b(e);
            p += e;
        }
        p += __shfl_xor(p, 1);
        p += __shfl_xor(p, 2);
        p += __shfl_xor(p, 4);
        p += __shfl_xor(p, 8);
        if (ln == 0) atomicAdd(&sS[row], p);
#pragma unroll
        for (int ct = 0; ct < 10; ++ct) gv[ct] = gn[ct];
    }

    // ---------------- Phase 3: out = (y @ cb) / S ----------------
    f32x4 acc2[2][8];
#pragma unroll
    for (int rt = 0; rt < 2; ++rt)
#pragma unroll
        for (int ct = 0; ct < 8; ++ct) acc2[rt][ct] = fz;

    const int g  = w >> 1;          // group
    const int nb = (w & 1) * 128;   // col block within group

#pragma unroll 1
    for (int ks = 0; ks < 10; ++ks) {
        const int k0 = ks * 32;
        __syncthreads();   // orders phase-2 y/S writes before first reads; reuses cb region
#pragma unroll
        for (int i = 0; i < 8; ++i) {
            int cbase = i * 256 + (w << 6);
            int c = cbase + l;
            int gg = c >> 10;
            int cc = c & 1023;
            int n = cc >> 2;
            int q2 = (cc & 3) ^ ((n >> 1) & 3);
            gl2lds16(cbT + (gg * DD + n) * ENTRY + k0 + q2 * 8, cS + cbase * 16);
        }
        __syncthreads();
        bf16x8 af[2];
#pragma unroll
        for (int rt = 0; rt < 2; ++rt)
            af[rt] = *(const bf16x8*)((char*)yS + (rt * 16 + ln) * (Y_STR * 2) + (g * ENTRY + k0 + q * 8) * 2);
        bf16x8 bfr[8];
#pragma unroll
        for (int ct = 0; ct < 8; ++ct) {
            int n = nb + ct * 16 + ln;
            int ch = (g << 10) + n * 4 + (q ^ ((n >> 1) & 3));
            bfr[ct] = *(const bf16x8*)(cS + ch * 16);
        }
#pragma unroll
        for (int rt = 0; rt < 2; ++rt)
#pragma unroll
            for (int ct = 0; ct < 8; ++ct)
                acc2[rt][ct] = __builtin_amdgcn_mfma_f32_16x16x32_bf16(af[rt], bfr[ct], acc2[rt][ct], 0, 0, 0);
    }

    // epilogue: divide by softmax denom, store fp32
#pragma unroll
    for (int rt = 0; rt < 2; ++rt) {
#pragma unroll
        for (int r = 0; r < 4; ++r) {
            int row = rt * 16 + q * 4 + r;
            float inv = 1.0f / sS[row];
            int orow = (rowbase + row) * 512;
#pragma unroll
            for (int ct = 0; ct < 8; ++ct) {
                int col = g * DD + nb + ct * 16 + ln;
                out[orow + col] = acc2[rt][ct][r] * inv;
            }
        }
    }
}

extern "C" void kernel_launch(void* const* d_in, const int* in_sizes, int n_in,
                              void* d_out, int out_size, void* d_ws, size_t ws_size,
                              hipStream_t stream) {
    const float* x   = (const float*)d_in[0];
    const float* Wp  = (const float*)d_in[1];
    const float* bp  = (const float*)d_in[2];
    const float* cb  = (const float*)d_in[3];
    const float* gum = (const float*)d_in[4];
    float* out = (float*)d_out;

    unsigned short* WpB = (unsigned short*)d_ws;
    unsigned short* cbT = WpB + NE * CIN;

    int prep_total = NE * CIN + 2 * ENTRY * DD;
    prep_kernel<<<(prep_total + 255) / 256, 256, 0, stream>>>(Wp, cb, WpB, cbT);

    fused_kernel<<<dim3(BT / MROWS), dim3(TPB), SMEM_BYTES, stream>>>(x, bp, gum, WpB, cbT, out);
}